// Round 3
// baseline (11923.555 us; speedup 1.0000x reference)
//
#include <hip/hip_runtime.h>
#include <stdint.h>

#define RB 8
#define QN 4096
#define DN 512
#define LN 256
#define NITERS 25

// ---------------- Threefry-2x32 (exact JAX algorithm) ----------------
__device__ __forceinline__ void tf2x32(uint32_t k0, uint32_t k1,
                                       uint32_t x0, uint32_t x1,
                                       uint32_t& y0, uint32_t& y1) {
  uint32_t ks2 = k0 ^ k1 ^ 0x1BD11BDAu;
#define TFR(r) { x0 += x1; x1 = (x1 << (r)) | (x1 >> (32 - (r))); x1 ^= x0; }
  x0 += k0; x1 += k1;
  TFR(13) TFR(15) TFR(26) TFR(6)   x0 += k1;  x1 += ks2 + 1u;
  TFR(17) TFR(29) TFR(16) TFR(24)  x0 += ks2; x1 += k0 + 2u;
  TFR(13) TFR(15) TFR(26) TFR(6)   x0 += k0;  x1 += k1 + 3u;
  TFR(17) TFR(29) TFR(16) TFR(24)  x0 += k1;  x1 += ks2 + 4u;
  TFR(13) TFR(15) TFR(26) TFR(6)   x0 += ks2; x1 += k0 + 5u;
#undef TFR
  y0 = x0; y1 = x1;
}

// One block per batch: jax.random.permutation(keys[b], 4096)[:256] under
// jax_threefry_partitionable=True:
//   split(key, n):  keys[i] = full (y0,y1) of threefry(key, counter=(0,i))
//   random_bits(k, 32, (n,)): bits[i] = y0 ^ y1 of threefry(k, counter=(0,i))
//   shuffle: 2 rounds of {key,sub = split(key); stable sort by random_bits}
__global__ __launch_bounds__(256) void k_init(const float* __restrict__ x,
                                              float* __restrict__ centers) {
  __shared__ unsigned long long comp[QN];   // (sortkey<<32)|pos -> stable sort
  __shared__ unsigned short perm[QN];
  __shared__ unsigned short ptmp[QN];
  const int b = blockIdx.x, t = threadIdx.x;

  uint32_t kb0, kb1;
  tf2x32(0u, 42u, 0u, (uint32_t)b, kb0, kb1);

  for (int i = t; i < QN; i += 256) perm[i] = (unsigned short)i;
  __syncthreads();

  for (int round = 0; round < 2; ++round) {
    uint32_t nk0, nk1, sk0, sk1;
    tf2x32(kb0, kb1, 0u, 0u, nk0, nk1);
    tf2x32(kb0, kb1, 0u, 1u, sk0, sk1);
    kb0 = nk0; kb1 = nk1;
    for (int i = t; i < QN; i += 256) {
      uint32_t y0, y1;
      tf2x32(sk0, sk1, 0u, (uint32_t)i, y0, y1);
      uint32_t bits = y0 ^ y1;
      comp[i] = ((unsigned long long)bits << 32) | (unsigned)i;
    }
    __syncthreads();
    for (int k = 2; k <= QN; k <<= 1) {
      for (int j = k >> 1; j > 0; j >>= 1) {
        for (int i = t; i < QN; i += 256) {
          int ixj = i ^ j;
          if (ixj > i) {
            unsigned long long vi = comp[i], vj = comp[ixj];
            bool up = ((i & k) == 0);
            bool sw = up ? (vi > vj) : (vi < vj);
            if (sw) { comp[i] = vj; comp[ixj] = vi; }
          }
        }
        __syncthreads();
      }
    }
    for (int i = t; i < QN; i += 256) ptmp[i] = perm[(unsigned)(comp[i] & 0xFFFFu)];
    __syncthreads();
    for (int i = t; i < QN; i += 256) perm[i] = ptmp[i];
    __syncthreads();
  }

  const float4* xb = (const float4*)(x + (size_t)b * QN * DN);
  float4* cb = (float4*)(centers + (size_t)b * LN * DN);
  for (int e = t; e < LN * (DN / 4); e += 256) {
    int row = e >> 7;
    int c = e & 127;
    cb[(size_t)row * 128 + c] = xb[(size_t)perm[row] * 128 + c];
  }
}

// Row-wise sum of squares (wave per row), fp32 out (only used as a shared
// per-point shift that cancels in softmax/argmin)
__global__ __launch_bounds__(256) void k_rowsq(const float* __restrict__ a,
                                               float* __restrict__ o, int nrows) {
  int w = (blockIdx.x * 256 + threadIdx.x) >> 6;
  int lane = threadIdx.x & 63;
  if (w >= nrows) return;
  const float* row = a + (size_t)w * DN;
  float s = 0.f;
  for (int i = lane; i < DN; i += 64) { float v = row[i]; s = fmaf(v, v, s); }
#pragma unroll
  for (int off = 32; off; off >>= 1) s += __shfl_down(s, off);
  if (lane == 0) o[w] = s;
}

// Row-wise sum of squares in fp64 (per-center bias must be exact)
__global__ __launch_bounds__(256) void k_rowsq_d(const float* __restrict__ a,
                                                 double* __restrict__ o, int nrows) {
  int w = (blockIdx.x * 256 + threadIdx.x) >> 6;
  int lane = threadIdx.x & 63;
  if (w >= nrows) return;
  const float* row = a + (size_t)w * DN;
  double s = 0.0;
  for (int i = lane; i < DN; i += 64) { double v = (double)row[i]; s = fma(v, v, s); }
#pragma unroll
  for (int off = 32; off; off >>= 1) s += __shfl_down(s, off);
  if (lane == 0) o[w] = s;
}

#define QT 64
#define DK 32

// dist (fp64) -> softmax (fp64) -> W (fp32). 512 threads, tile 64q x 256l,
// per-thread 4 rows x 8 cols, fp64 accumulation.
__global__ __launch_bounds__(512) void k_assign(const float* __restrict__ x,
                                                const float* __restrict__ centers,
                                                const float* __restrict__ xsq,
                                                const double* __restrict__ csqd,
                                                float* __restrict__ W) {
  __shared__ float xsT[DK][QT + 4];
  __shared__ float csT[DK][LN + 4];
  __shared__ double redd[QT][33];
  const int b = blockIdx.y;
  const int q0 = blockIdx.x * QT;
  const int t = threadIdx.x;
  const int rg = t & 15;    // rows rg*4..+3
  const int cg = t >> 4;    // cols cg*8..+7
  double acc[4][8];
#pragma unroll
  for (int i = 0; i < 4; i++)
#pragma unroll
    for (int j = 0; j < 8; j++) acc[i][j] = 0.0;

  const float* xb = x + ((size_t)b * QN + q0) * DN;
  const float* cb = centers + (size_t)b * LN * DN;

  for (int d0 = 0; d0 < DN; d0 += DK) {
    {
      int row = t >> 3, c4 = t & 7;
      float4 v = *(const float4*)(xb + (size_t)row * DN + d0 + c4 * 4);
      xsT[c4 * 4 + 0][row] = v.x; xsT[c4 * 4 + 1][row] = v.y;
      xsT[c4 * 4 + 2][row] = v.z; xsT[c4 * 4 + 3][row] = v.w;
    }
#pragma unroll
    for (int i = 0; i < 4; i++) {
      int f = t + 512 * i;
      int row = f >> 3, c4 = f & 7;
      float4 v = *(const float4*)(cb + (size_t)row * DN + d0 + c4 * 4);
      csT[c4 * 4 + 0][row] = v.x; csT[c4 * 4 + 1][row] = v.y;
      csT[c4 * 4 + 2][row] = v.z; csT[c4 * 4 + 3][row] = v.w;
    }
    __syncthreads();
#pragma unroll
    for (int k = 0; k < DK; k++) {
      float4 xv = *(const float4*)&xsT[k][rg * 4];
      float4 c0 = *(const float4*)&csT[k][cg * 8];
      float4 c1 = *(const float4*)&csT[k][cg * 8 + 4];
      double xd[4] = {(double)xv.x, (double)xv.y, (double)xv.z, (double)xv.w};
      double cd[8] = {(double)c0.x, (double)c0.y, (double)c0.z, (double)c0.w,
                      (double)c1.x, (double)c1.y, (double)c1.z, (double)c1.w};
#pragma unroll
      for (int i = 0; i < 4; i++)
#pragma unroll
        for (int j = 0; j < 8; j++)
          acc[i][j] = fma(xd[i], cd[j], acc[i][j]);
    }
    __syncthreads();
  }

  double csqv[8], xsqv[4];
#pragma unroll
  for (int j = 0; j < 8; j++) csqv[j] = csqd[b * LN + cg * 8 + j];
#pragma unroll
  for (int i = 0; i < 4; i++) xsqv[i] = (double)xsq[b * QN + q0 + rg * 4 + i];

  // logits (fp64), row max
  double lmax[4];
#pragma unroll
  for (int i = 0; i < 4; i++) {
    double m = -1e300;
#pragma unroll
    for (int j = 0; j < 8; j++) {
      double dd = xsqv[i] - 2.0 * acc[i][j] + csqv[j];
      double lg = -5.0 * dd;
      acc[i][j] = lg;
      m = fmax(m, lg);
    }
    lmax[i] = m;
  }
#pragma unroll
  for (int i = 0; i < 4; i++) redd[rg * 4 + i][cg] = lmax[i];
  __syncthreads();
  double rmax[4];
#pragma unroll
  for (int i = 0; i < 4; i++) {
    double m = -1e300;
    for (int c = 0; c < 32; c++) m = fmax(m, redd[rg * 4 + i][c]);
    rmax[i] = m;
  }
  __syncthreads();
#pragma unroll
  for (int i = 0; i < 4; i++) {
    double s = 0.0;
#pragma unroll
    for (int j = 0; j < 8; j++) {
      double e = exp(acc[i][j] - rmax[i]);
      acc[i][j] = e;
      s += e;
    }
    redd[rg * 4 + i][cg] = s;
  }
  __syncthreads();
#pragma unroll
  for (int i = 0; i < 4; i++) {
    double s = 0.0;
    for (int c = 0; c < 32; c++) s += redd[rg * 4 + i][c];
    float* wrow = W + ((size_t)b * QN + q0 + rg * 4 + i) * LN + cg * 8;
    float4 v0 = make_float4((float)(acc[i][0] / s), (float)(acc[i][1] / s),
                            (float)(acc[i][2] / s), (float)(acc[i][3] / s));
    float4 v1 = make_float4((float)(acc[i][4] / s), (float)(acc[i][5] / s),
                            (float)(acc[i][6] / s), (float)(acc[i][7] / s));
    *(float4*)wrow = v0;
    *(float4*)(wrow + 4) = v1;
  }
}

#define LT 64
#define DT 64
#define KQ 32

// Cnew[l][d] = sum_q W[q][l] * X[q][d] / (sum_q W[q][l] + eps)  (fp32)
__global__ __launch_bounds__(256) void k_update(const float* __restrict__ W,
                                                const float* __restrict__ x,
                                                float* __restrict__ cnew) {
  __shared__ float wT[KQ][LT + 4];
  __shared__ float xT[KQ][DT + 4];
  const int b = blockIdx.z;
  const int l0 = blockIdx.x * LT;
  const int d0 = blockIdx.y * DT;
  const int t = threadIdx.x;
  const int rg = t & 15;
  const int cg = t >> 4;
  float acc[4][4];
#pragma unroll
  for (int i = 0; i < 4; i++)
#pragma unroll
    for (int j = 0; j < 4; j++) acc[i][j] = 0.f;
  float dsum[4] = {0.f, 0.f, 0.f, 0.f};
  const float* Wb = W + (size_t)b * QN * LN;
  const float* xb = x + (size_t)b * QN * DN;

  for (int k0 = 0; k0 < QN; k0 += KQ) {
#pragma unroll
    for (int i = 0; i < 2; i++) {
      int f = t + 256 * i;
      int row = f >> 4, c4 = f & 15;
      float4 v = *(const float4*)(Wb + (size_t)(k0 + row) * LN + l0 + c4 * 4);
      *(float4*)&wT[row][c4 * 4] = v;
    }
#pragma unroll
    for (int i = 0; i < 2; i++) {
      int f = t + 256 * i;
      int row = f >> 4, c4 = f & 15;
      float4 v = *(const float4*)(xb + (size_t)(k0 + row) * DN + d0 + c4 * 4);
      *(float4*)&xT[row][c4 * 4] = v;
    }
    __syncthreads();
#pragma unroll
    for (int k = 0; k < KQ; k++) {
      float wf[4], xf[4];
      *(float4*)wf = *(const float4*)&wT[k][rg * 4];
      *(float4*)xf = *(const float4*)&xT[k][cg * 4];
#pragma unroll
      for (int i = 0; i < 4; i++) {
        dsum[i] += wf[i];
#pragma unroll
        for (int j = 0; j < 4; j++) acc[i][j] = fmaf(wf[i], xf[j], acc[i][j]);
      }
    }
    __syncthreads();
  }
#pragma unroll
  for (int i = 0; i < 4; i++) {
    float den = dsum[i] + 1e-9f;
    float4 v = make_float4(acc[i][0] / den, acc[i][1] / den,
                           acc[i][2] / den, acc[i][3] / den);
    *(float4*)(cnew + ((size_t)b * LN + l0 + rg * 4 + i) * DN + d0 + cg * 4) = v;
  }
}

// fp64 dist -> argmin -> gather centroid rows to out. 512 threads.
__global__ __launch_bounds__(512) void k_final(const float* __restrict__ x,
                                               const float* __restrict__ centers,
                                               const float* __restrict__ xsq,
                                               const double* __restrict__ csqd,
                                               float* __restrict__ out) {
  __shared__ float xsT[DK][QT + 4];
  __shared__ float csT[DK][LN + 4];
  __shared__ double redv[QT][33];
  __shared__ unsigned short redi[QT][33];
  __shared__ unsigned short labels[QT];
  const int b = blockIdx.y;
  const int q0 = blockIdx.x * QT;
  const int t = threadIdx.x;
  const int rg = t & 15;
  const int cg = t >> 4;
  double acc[4][8];
#pragma unroll
  for (int i = 0; i < 4; i++)
#pragma unroll
    for (int j = 0; j < 8; j++) acc[i][j] = 0.0;

  const float* xb = x + ((size_t)b * QN + q0) * DN;
  const float* cb = centers + (size_t)b * LN * DN;

  for (int d0 = 0; d0 < DN; d0 += DK) {
    {
      int row = t >> 3, c4 = t & 7;
      float4 v = *(const float4*)(xb + (size_t)row * DN + d0 + c4 * 4);
      xsT[c4 * 4 + 0][row] = v.x; xsT[c4 * 4 + 1][row] = v.y;
      xsT[c4 * 4 + 2][row] = v.z; xsT[c4 * 4 + 3][row] = v.w;
    }
#pragma unroll
    for (int i = 0; i < 4; i++) {
      int f = t + 512 * i;
      int row = f >> 3, c4 = f & 7;
      float4 v = *(const float4*)(cb + (size_t)row * DN + d0 + c4 * 4);
      csT[c4 * 4 + 0][row] = v.x; csT[c4 * 4 + 1][row] = v.y;
      csT[c4 * 4 + 2][row] = v.z; csT[c4 * 4 + 3][row] = v.w;
    }
    __syncthreads();
#pragma unroll
    for (int k = 0; k < DK; k++) {
      float4 xv = *(const float4*)&xsT[k][rg * 4];
      float4 c0 = *(const float4*)&csT[k][cg * 8];
      float4 c1 = *(const float4*)&csT[k][cg * 8 + 4];
      double xd[4] = {(double)xv.x, (double)xv.y, (double)xv.z, (double)xv.w};
      double cd[8] = {(double)c0.x, (double)c0.y, (double)c0.z, (double)c0.w,
                      (double)c1.x, (double)c1.y, (double)c1.z, (double)c1.w};
#pragma unroll
      for (int i = 0; i < 4; i++)
#pragma unroll
        for (int j = 0; j < 8; j++)
          acc[i][j] = fma(xd[i], cd[j], acc[i][j]);
    }
    __syncthreads();
  }

  double csqv[8], xsqv[4];
#pragma unroll
  for (int j = 0; j < 8; j++) csqv[j] = csqd[b * LN + cg * 8 + j];
#pragma unroll
  for (int i = 0; i < 4; i++) xsqv[i] = (double)xsq[b * QN + q0 + rg * 4 + i];

  double bv[4]; int bi[4];
#pragma unroll
  for (int i = 0; i < 4; i++) {
    bv[i] = 1e300; bi[i] = 0;
#pragma unroll
    for (int j = 0; j < 8; j++) {
      double dd = xsqv[i] - 2.0 * acc[i][j] + csqv[j];
      if (dd < bv[i]) { bv[i] = dd; bi[i] = cg * 8 + j; }
    }
  }
#pragma unroll
  for (int i = 0; i < 4; i++) {
    redv[rg * 4 + i][cg] = bv[i];
    redi[rg * 4 + i][cg] = (unsigned short)bi[i];
  }
  __syncthreads();
  if (t < 16) {
#pragma unroll
    for (int i = 0; i < 4; i++) {
      double best = 1e300; int bidx = 0;
      for (int c = 0; c < 32; c++) {
        double v = redv[t * 4 + i][c];
        int id = redi[t * 4 + i][c];
        if (v < best || (v == best && id < bidx)) { best = v; bidx = id; }
      }
      labels[t * 4 + i] = (unsigned short)bidx;
    }
  }
  __syncthreads();
  const float4* cb4 = (const float4*)(centers + (size_t)b * LN * DN);
  float4* ob = (float4*)(out + ((size_t)b * QN + q0) * DN);
  for (int e = t; e < QT * (DN / 4); e += 512) {
    int row = e >> 7, c = e & 127;
    ob[(size_t)row * 128 + c] = cb4[(size_t)labels[row] * 128 + c];
  }
}

extern "C" void kernel_launch(void* const* d_in, const int* in_sizes, int n_in,
                              void* d_out, int out_size, void* d_ws, size_t ws_size,
                              hipStream_t stream) {
  const float* x = (const float*)d_in[0];
  float* out = (float*)d_out;

  const size_t szC    = (size_t)RB * LN * DN * sizeof(float);   // 4 MB
  const size_t szXsq  = (size_t)RB * QN * sizeof(float);        // 128 KB
  const size_t szCsqD = (size_t)RB * LN * sizeof(double);       // 16 KB
  const size_t szW    = (size_t)RB * QN * LN * sizeof(float);   // 33.5 MB

  char* p = (char*)d_ws;
  float*  cA   = (float*)p;  p += szC;
  float*  cB   = (float*)p;  p += szC;
  float*  xsq  = (float*)p;  p += szXsq;
  double* csqd = (double*)p; p += szCsqD;
  float* W;
  if (ws_size >= 2 * szC + szXsq + szCsqD + szW) {
    W = (float*)p;
  } else {
    // out buffer (67 MB) as scratch for W; k_final rewrites it afterwards
    W = (float*)d_out;
  }

  k_init<<<RB, 256, 0, stream>>>(x, cA);
  k_rowsq<<<(RB * QN) / 4, 256, 0, stream>>>(x, xsq, RB * QN);
  k_rowsq_d<<<(RB * LN) / 4, 256, 0, stream>>>(cA, csqd, RB * LN);

  float* cur = cA;
  float* nxt = cB;
  for (int it = 0; it < NITERS; ++it) {
    k_assign<<<dim3(QN / QT, RB), 512, 0, stream>>>(x, cur, xsq, csqd, W);
    k_update<<<dim3(LN / LT, DN / DT, RB), 256, 0, stream>>>(W, x, nxt);
    k_rowsq_d<<<(RB * LN) / 4, 256, 0, stream>>>(nxt, csqd, RB * LN);
    float* tmp = cur; cur = nxt; nxt = tmp;
  }
  k_final<<<dim3(QN / QT, RB), 512, 0, stream>>>(x, cur, xsq, csqd, out);
}

// Round 4
// 10886.886 us; speedup vs baseline: 1.0952x; 1.0952x over previous
//
#include <hip/hip_runtime.h>
#include <stdint.h>

#define RB 8
#define QN 4096
#define DN 512
#define LN 256
#define NITERS 25

// ---------------- Threefry-2x32 (exact JAX algorithm) ----------------
__device__ __forceinline__ void tf2x32(uint32_t k0, uint32_t k1,
                                       uint32_t x0, uint32_t x1,
                                       uint32_t& y0, uint32_t& y1) {
  uint32_t ks2 = k0 ^ k1 ^ 0x1BD11BDAu;
#define TFR(r) { x0 += x1; x1 = (x1 << (r)) | (x1 >> (32 - (r))); x1 ^= x0; }
  x0 += k0; x1 += k1;
  TFR(13) TFR(15) TFR(26) TFR(6)   x0 += k1;  x1 += ks2 + 1u;
  TFR(17) TFR(29) TFR(16) TFR(24)  x0 += ks2; x1 += k0 + 2u;
  TFR(13) TFR(15) TFR(26) TFR(6)   x0 += k0;  x1 += k1 + 3u;
  TFR(17) TFR(29) TFR(16) TFR(24)  x0 += k1;  x1 += ks2 + 4u;
  TFR(13) TFR(15) TFR(26) TFR(6)   x0 += ks2; x1 += k0 + 5u;
#undef TFR
  y0 = x0; y1 = x1;
}

// One block per batch: jax.random.permutation(keys[b], 4096)[:256] under
// jax_threefry_partitionable=True (verified round 2->3):
//   split(key, n):  keys[i] = full (y0,y1) of threefry(key, counter=(0,i))
//   random_bits(k, 32, (n,)): bits[i] = y0 ^ y1 of threefry(k, counter=(0,i))
//   shuffle: 2 rounds of {key,sub = split(key); stable sort by random_bits}
__global__ __launch_bounds__(1024) void k_init(const float* __restrict__ x,
                                               float* __restrict__ centers) {
  __shared__ unsigned long long comp[QN];   // (sortkey<<32)|pos -> stable sort
  __shared__ unsigned short perm[QN];
  __shared__ unsigned short ptmp[QN];
  const int b = blockIdx.x, t = threadIdx.x;

  uint32_t kb0, kb1;
  tf2x32(0u, 42u, 0u, (uint32_t)b, kb0, kb1);

  for (int i = t; i < QN; i += 1024) perm[i] = (unsigned short)i;
  __syncthreads();

  for (int round = 0; round < 2; ++round) {
    uint32_t nk0, nk1, sk0, sk1;
    tf2x32(kb0, kb1, 0u, 0u, nk0, nk1);
    tf2x32(kb0, kb1, 0u, 1u, sk0, sk1);
    kb0 = nk0; kb1 = nk1;
    for (int i = t; i < QN; i += 1024) {
      uint32_t y0, y1;
      tf2x32(sk0, sk1, 0u, (uint32_t)i, y0, y1);
      uint32_t bits = y0 ^ y1;
      comp[i] = ((unsigned long long)bits << 32) | (unsigned)i;
    }
    __syncthreads();
    for (int k = 2; k <= QN; k <<= 1) {
      for (int j = k >> 1; j > 0; j >>= 1) {
        for (int i = t; i < QN; i += 1024) {
          int ixj = i ^ j;
          if (ixj > i) {
            unsigned long long vi = comp[i], vj = comp[ixj];
            bool up = ((i & k) == 0);
            bool sw = up ? (vi > vj) : (vi < vj);
            if (sw) { comp[i] = vj; comp[ixj] = vi; }
          }
        }
        __syncthreads();
      }
    }
    for (int i = t; i < QN; i += 1024) ptmp[i] = perm[(unsigned)(comp[i] & 0xFFFFu)];
    __syncthreads();
    for (int i = t; i < QN; i += 1024) perm[i] = ptmp[i];
    __syncthreads();
  }

  const float4* xb = (const float4*)(x + (size_t)b * QN * DN);
  float4* cb = (float4*)(centers + (size_t)b * LN * DN);
  for (int e = t; e < LN * (DN / 4); e += 1024) {
    int row = e >> 7;
    int c = e & 127;
    cb[(size_t)row * 128 + c] = xb[(size_t)perm[row] * 128 + c];
  }
}

// Row-wise sum of squares in fp64 (per-center bias must be exact)
__global__ __launch_bounds__(256) void k_rowsq_d(const float* __restrict__ a,
                                                 double* __restrict__ o, int nrows) {
  int w = (blockIdx.x * 256 + threadIdx.x) >> 6;
  int lane = threadIdx.x & 63;
  if (w >= nrows) return;
  const float* row = a + (size_t)w * DN;
  double s = 0.0;
  for (int i = lane; i < DN; i += 64) { double v = (double)row[i]; s = fma(v, v, s); }
#pragma unroll
  for (int off = 32; off; off >>= 1) s += __shfl_down(s, off);
  if (lane == 0) o[w] = s;
}

#define QT 64
#define DK 16
// grouped-column layout: 8 payload doubles + 2 pad per group of 8 columns
// -> the 8 group base addresses per wave land on 8 distinct bank-quads.
#define XLD 80    // 8 groups  * 10
#define CLD 320   // 32 groups * 10
__device__ __forceinline__ int grow(int c) { return c + ((c >> 3) << 1); }

// dist (fp64, tiles pre-converted in LDS) -> softmax (fp64) -> W (fp32).
// 256 threads, tile 64q x 256l, per-thread 8x8 fp64 acc.
__global__ __launch_bounds__(256, 2) void k_assign(const float* __restrict__ x,
                                                   const float* __restrict__ centers,
                                                   const double* __restrict__ csqd,
                                                   float* __restrict__ W) {
  __shared__ double arena[DK * XLD + DK * CLD];   // 51.2 KB
  double (*xsD)[XLD] = (double(*)[XLD])arena;
  double (*csD)[CLD] = (double(*)[CLD])(arena + DK * XLD);
  double (*red)[33]  = (double(*)[33])arena;      // aliased after k-loop

  const int b = blockIdx.y;
  const int q0 = blockIdx.x * QT;
  const int t = threadIdx.x;
  const int rg = t & 7;     // q-rows  rg*8 .. +7
  const int cg = t >> 3;    // l-cols  cg*8 .. +7
  double acc[8][8];
#pragma unroll
  for (int i = 0; i < 8; i++)
#pragma unroll
    for (int j = 0; j < 8; j++) acc[i][j] = 0.0;

  const float* xb = x + ((size_t)b * QN + q0) * DN;
  const float* cb = centers + (size_t)b * LN * DN;

  for (int d0 = 0; d0 < DN; d0 += DK) {
    {   // x-tile: 64 rows x 16 cols -> transposed fp64
      int row = t >> 2, c4 = t & 3;
      float4 v = *(const float4*)(xb + (size_t)row * DN + d0 + c4 * 4);
      int g = grow(row);
      xsD[c4 * 4 + 0][g] = (double)v.x; xsD[c4 * 4 + 1][g] = (double)v.y;
      xsD[c4 * 4 + 2][g] = (double)v.z; xsD[c4 * 4 + 3][g] = (double)v.w;
    }
#pragma unroll
    for (int i = 0; i < 4; i++) {   // c-tile: 256 rows x 16 cols
      int f = t + 256 * i;
      int row = f >> 2, c4 = f & 3;
      float4 v = *(const float4*)(cb + (size_t)row * DN + d0 + c4 * 4);
      int g = grow(row);
      csD[c4 * 4 + 0][g] = (double)v.x; csD[c4 * 4 + 1][g] = (double)v.y;
      csD[c4 * 4 + 2][g] = (double)v.z; csD[c4 * 4 + 3][g] = (double)v.w;
    }
    __syncthreads();
#pragma unroll
    for (int k = 0; k < DK; k++) {
      double xv[8], cv[8];
      const double* xp = &xsD[k][rg * 10];
      const double* cp = &csD[k][cg * 10];
#pragma unroll
      for (int j = 0; j < 8; j++) xv[j] = xp[j];
#pragma unroll
      for (int j = 0; j < 8; j++) cv[j] = cp[j];
#pragma unroll
      for (int i = 0; i < 8; i++)
#pragma unroll
        for (int j = 0; j < 8; j++)
          acc[i][j] = fma(xv[i], cv[j], acc[i][j]);
    }
    __syncthreads();
  }

  double csqv[8];
#pragma unroll
  for (int j = 0; j < 8; j++) csqv[j] = csqd[b * LN + cg * 8 + j];

  // logits (xsq shift dropped -- cancels exactly against the row max)
  double lmax[8];
#pragma unroll
  for (int i = 0; i < 8; i++) {
    double m = -1e300;
#pragma unroll
    for (int j = 0; j < 8; j++) {
      double lg = -5.0 * (csqv[j] - 2.0 * acc[i][j]);
      acc[i][j] = lg;
      m = fmax(m, lg);
    }
    lmax[i] = m;
  }
#pragma unroll
  for (int i = 0; i < 8; i++) red[rg * 8 + i][cg] = lmax[i];
  __syncthreads();
  double rmax[8];
#pragma unroll
  for (int i = 0; i < 8; i++) {
    double m = -1e300;
    for (int c = 0; c < 32; c++) m = fmax(m, red[rg * 8 + i][c]);
    rmax[i] = m;
  }
  __syncthreads();
#pragma unroll
  for (int i = 0; i < 8; i++) {
    double s = 0.0;
#pragma unroll
    for (int j = 0; j < 8; j++) {
      double e = exp(acc[i][j] - rmax[i]);
      acc[i][j] = e;
      s += e;
    }
    red[rg * 8 + i][cg] = s;
  }
  __syncthreads();
#pragma unroll
  for (int i = 0; i < 8; i++) {
    double s = 0.0;
    for (int c = 0; c < 32; c++) s += red[rg * 8 + i][c];
    float* wrow = W + ((size_t)b * QN + q0 + rg * 8 + i) * LN + cg * 8;
    float4 v0 = make_float4((float)(acc[i][0] / s), (float)(acc[i][1] / s),
                            (float)(acc[i][2] / s), (float)(acc[i][3] / s));
    float4 v1 = make_float4((float)(acc[i][4] / s), (float)(acc[i][5] / s),
                            (float)(acc[i][6] / s), (float)(acc[i][7] / s));
    *(float4*)wrow = v0;
    *(float4*)(wrow + 4) = v1;
  }
}

#define LT 64
#define DT 64
#define KQ 32

// Cnew[l][d] = sum_q W[q][l] * X[q][d] / (sum_q W[q][l] + eps)  (fp32)
__global__ __launch_bounds__(256) void k_update(const float* __restrict__ W,
                                                const float* __restrict__ x,
                                                float* __restrict__ cnew) {
  __shared__ float wT[KQ][LT + 4];
  __shared__ float xT[KQ][DT + 4];
  const int b = blockIdx.z;
  const int l0 = blockIdx.x * LT;
  const int d0 = blockIdx.y * DT;
  const int t = threadIdx.x;
  const int rg = t & 15;
  const int cg = t >> 4;
  float acc[4][4];
#pragma unroll
  for (int i = 0; i < 4; i++)
#pragma unroll
    for (int j = 0; j < 4; j++) acc[i][j] = 0.f;
  float dsum[4] = {0.f, 0.f, 0.f, 0.f};
  const float* Wb = W + (size_t)b * QN * LN;
  const float* xb = x + (size_t)b * QN * DN;

  for (int k0 = 0; k0 < QN; k0 += KQ) {
#pragma unroll
    for (int i = 0; i < 2; i++) {
      int f = t + 256 * i;
      int row = f >> 4, c4 = f & 15;
      float4 v = *(const float4*)(Wb + (size_t)(k0 + row) * LN + l0 + c4 * 4);
      *(float4*)&wT[row][c4 * 4] = v;
    }
#pragma unroll
    for (int i = 0; i < 2; i++) {
      int f = t + 256 * i;
      int row = f >> 4, c4 = f & 15;
      float4 v = *(const float4*)(xb + (size_t)(k0 + row) * DN + d0 + c4 * 4);
      *(float4*)&xT[row][c4 * 4] = v;
    }
    __syncthreads();
#pragma unroll
    for (int k = 0; k < KQ; k++) {
      float wf[4], xf[4];
      *(float4*)wf = *(const float4*)&wT[k][rg * 4];
      *(float4*)xf = *(const float4*)&xT[k][cg * 4];
#pragma unroll
      for (int i = 0; i < 4; i++) {
        dsum[i] += wf[i];
#pragma unroll
        for (int j = 0; j < 4; j++) acc[i][j] = fmaf(wf[i], xf[j], acc[i][j]);
      }
    }
    __syncthreads();
  }
#pragma unroll
  for (int i = 0; i < 4; i++) {
    float den = dsum[i] + 1e-9f;
    float4 v = make_float4(acc[i][0] / den, acc[i][1] / den,
                           acc[i][2] / den, acc[i][3] / den);
    *(float4*)(cnew + ((size_t)b * LN + l0 + rg * 4 + i) * DN + d0 + cg * 4) = v;
  }
}

// fp64 dist -> argmin -> gather centroid rows to out. Same GEMM as k_assign.
__global__ __launch_bounds__(256, 2) void k_final(const float* __restrict__ x,
                                                  const float* __restrict__ centers,
                                                  const double* __restrict__ csqd,
                                                  float* __restrict__ out) {
  __shared__ double arena[DK * XLD + DK * CLD];
  double (*xsD)[XLD] = (double(*)[XLD])arena;
  double (*csD)[CLD] = (double(*)[CLD])(arena + DK * XLD);
  double (*redv)[33] = (double(*)[33])arena;      // aliased after k-loop
  __shared__ unsigned short redi[QT][33];
  __shared__ unsigned short labels[QT];

  const int b = blockIdx.y;
  const int q0 = blockIdx.x * QT;
  const int t = threadIdx.x;
  const int rg = t & 7;
  const int cg = t >> 3;
  double acc[8][8];
#pragma unroll
  for (int i = 0; i < 8; i++)
#pragma unroll
    for (int j = 0; j < 8; j++) acc[i][j] = 0.0;

  const float* xb = x + ((size_t)b * QN + q0) * DN;
  const float* cb = centers + (size_t)b * LN * DN;

  for (int d0 = 0; d0 < DN; d0 += DK) {
    {
      int row = t >> 2, c4 = t & 3;
      float4 v = *(const float4*)(xb + (size_t)row * DN + d0 + c4 * 4);
      int g = grow(row);
      xsD[c4 * 4 + 0][g] = (double)v.x; xsD[c4 * 4 + 1][g] = (double)v.y;
      xsD[c4 * 4 + 2][g] = (double)v.z; xsD[c4 * 4 + 3][g] = (double)v.w;
    }
#pragma unroll
    for (int i = 0; i < 4; i++) {
      int f = t + 256 * i;
      int row = f >> 2, c4 = f & 3;
      float4 v = *(const float4*)(cb + (size_t)row * DN + d0 + c4 * 4);
      int g = grow(row);
      csD[c4 * 4 + 0][g] = (double)v.x; csD[c4 * 4 + 1][g] = (double)v.y;
      csD[c4 * 4 + 2][g] = (double)v.z; csD[c4 * 4 + 3][g] = (double)v.w;
    }
    __syncthreads();
#pragma unroll
    for (int k = 0; k < DK; k++) {
      double xv[8], cv[8];
      const double* xp = &xsD[k][rg * 10];
      const double* cp = &csD[k][cg * 10];
#pragma unroll
      for (int j = 0; j < 8; j++) xv[j] = xp[j];
#pragma unroll
      for (int j = 0; j < 8; j++) cv[j] = cp[j];
#pragma unroll
      for (int i = 0; i < 8; i++)
#pragma unroll
        for (int j = 0; j < 8; j++)
          acc[i][j] = fma(xv[i], cv[j], acc[i][j]);
    }
    __syncthreads();
  }

  double csqv[8];
#pragma unroll
  for (int j = 0; j < 8; j++) csqv[j] = csqd[b * LN + cg * 8 + j];

  // argmin key: csq - 2*dot (xsq shift dropped -- pure per-row shift)
  double bv[8]; int bi[8];
#pragma unroll
  for (int i = 0; i < 8; i++) {
    bv[i] = 1e300; bi[i] = 0;
#pragma unroll
    for (int j = 0; j < 8; j++) {
      double dd = csqv[j] - 2.0 * acc[i][j];
      if (dd < bv[i]) { bv[i] = dd; bi[i] = cg * 8 + j; }
    }
  }
#pragma unroll
  for (int i = 0; i < 8; i++) {
    redv[rg * 8 + i][cg] = bv[i];
    redi[rg * 8 + i][cg] = (unsigned short)bi[i];
  }
  __syncthreads();
  if (t < QT) {
    double best = 1e300; int bidx = 0;
    for (int c = 0; c < 32; c++) {
      double v = redv[t][c];
      int id = redi[t][c];
      if (v < best || (v == best && id < bidx)) { best = v; bidx = id; }
    }
    labels[t] = (unsigned short)bidx;
  }
  __syncthreads();
  const float4* cb4 = (const float4*)(centers + (size_t)b * LN * DN);
  float4* ob = (float4*)(out + ((size_t)b * QN + q0) * DN);
  for (int e = t; e < QT * (DN / 4); e += 256) {
    int row = e >> 7, c = e & 127;
    ob[(size_t)row * 128 + c] = cb4[(size_t)labels[row] * 128 + c];
  }
}

extern "C" void kernel_launch(void* const* d_in, const int* in_sizes, int n_in,
                              void* d_out, int out_size, void* d_ws, size_t ws_size,
                              hipStream_t stream) {
  const float* x = (const float*)d_in[0];
  float* out = (float*)d_out;

  const size_t szC    = (size_t)RB * LN * DN * sizeof(float);   // 4 MB
  const size_t szCsqD = (size_t)RB * LN * sizeof(double);       // 16 KB
  const size_t szW    = (size_t)RB * QN * LN * sizeof(float);   // 33.5 MB

  char* p = (char*)d_ws;
  float*  cA   = (float*)p;  p += szC;
  float*  cB   = (float*)p;  p += szC;
  double* csqd = (double*)p; p += szCsqD;
  float* W;
  if (ws_size >= 2 * szC + szCsqD + szW) {
    W = (float*)p;
  } else {
    // out buffer (67 MB) as scratch for W; k_final rewrites it afterwards
    W = (float*)d_out;
  }

  k_init<<<RB, 1024, 0, stream>>>(x, cA);
  k_rowsq_d<<<(RB * LN) / 4, 256, 0, stream>>>(cA, csqd, RB * LN);

  float* cur = cA;
  float* nxt = cB;
  for (int it = 0; it < NITERS; ++it) {
    k_assign<<<dim3(QN / QT, RB), 256, 0, stream>>>(x, cur, csqd, W);
    k_update<<<dim3(LN / LT, DN / DT, RB), 256, 0, stream>>>(W, x, nxt);
    k_rowsq_d<<<(RB * LN) / 4, 256, 0, stream>>>(nxt, csqd, RB * LN);
    float* tmp = cur; cur = nxt; nxt = tmp;
  }
  k_final<<<dim3(QN / QT, RB), 256, 0, stream>>>(x, cur, csqd, out);
}

// Round 5
// 7982.146 us; speedup vs baseline: 1.4938x; 1.3639x over previous
//
#include <hip/hip_runtime.h>
#include <stdint.h>

#define RB 8
#define QN 4096
#define DN 512
#define LN 256
#define NITERS 25

// ---------------- Threefry-2x32 (exact JAX algorithm) ----------------
__device__ __forceinline__ void tf2x32(uint32_t k0, uint32_t k1,
                                       uint32_t x0, uint32_t x1,
                                       uint32_t& y0, uint32_t& y1) {
  uint32_t ks2 = k0 ^ k1 ^ 0x1BD11BDAu;
#define TFR(r) { x0 += x1; x1 = (x1 << (r)) | (x1 >> (32 - (r))); x1 ^= x0; }
  x0 += k0; x1 += k1;
  TFR(13) TFR(15) TFR(26) TFR(6)   x0 += k1;  x1 += ks2 + 1u;
  TFR(17) TFR(29) TFR(16) TFR(24)  x0 += ks2; x1 += k0 + 2u;
  TFR(13) TFR(15) TFR(26) TFR(6)   x0 += k0;  x1 += k1 + 3u;
  TFR(17) TFR(29) TFR(16) TFR(24)  x0 += k1;  x1 += ks2 + 4u;
  TFR(13) TFR(15) TFR(26) TFR(6)   x0 += ks2; x1 += k0 + 5u;
#undef TFR
  y0 = x0; y1 = x1;
}

// jax.random.permutation under jax_threefry_partitionable=True (verified r2->r3)
__global__ __launch_bounds__(1024) void k_init(const float* __restrict__ x,
                                               float* __restrict__ centers) {
  __shared__ unsigned long long comp[QN];
  __shared__ unsigned short perm[QN];
  __shared__ unsigned short ptmp[QN];
  const int b = blockIdx.x, t = threadIdx.x;

  uint32_t kb0, kb1;
  tf2x32(0u, 42u, 0u, (uint32_t)b, kb0, kb1);

  for (int i = t; i < QN; i += 1024) perm[i] = (unsigned short)i;
  __syncthreads();

  for (int round = 0; round < 2; ++round) {
    uint32_t nk0, nk1, sk0, sk1;
    tf2x32(kb0, kb1, 0u, 0u, nk0, nk1);
    tf2x32(kb0, kb1, 0u, 1u, sk0, sk1);
    kb0 = nk0; kb1 = nk1;
    for (int i = t; i < QN; i += 1024) {
      uint32_t y0, y1;
      tf2x32(sk0, sk1, 0u, (uint32_t)i, y0, y1);
      uint32_t bits = y0 ^ y1;
      comp[i] = ((unsigned long long)bits << 32) | (unsigned)i;
    }
    __syncthreads();
    for (int k = 2; k <= QN; k <<= 1) {
      for (int j = k >> 1; j > 0; j >>= 1) {
        for (int i = t; i < QN; i += 1024) {
          int ixj = i ^ j;
          if (ixj > i) {
            unsigned long long vi = comp[i], vj = comp[ixj];
            bool up = ((i & k) == 0);
            bool sw = up ? (vi > vj) : (vi < vj);
            if (sw) { comp[i] = vj; comp[ixj] = vi; }
          }
        }
        __syncthreads();
      }
    }
    for (int i = t; i < QN; i += 1024) ptmp[i] = perm[(unsigned)(comp[i] & 0xFFFFu)];
    __syncthreads();
    for (int i = t; i < QN; i += 1024) perm[i] = ptmp[i];
    __syncthreads();
  }

  const float4* xb = (const float4*)(x + (size_t)b * QN * DN);
  float4* cb = (float4*)(centers + (size_t)b * LN * DN);
  for (int e = t; e < LN * (DN / 4); e += 1024) {
    int row = e >> 7;
    int c = e & 127;
    cb[(size_t)row * 128 + c] = xb[(size_t)perm[row] * 128 + c];
  }
}

// fp64 row sum-of-squares (used once after init; reduce kernel fuses it later)
__global__ __launch_bounds__(256) void k_rowsq_d(const float* __restrict__ a,
                                                 double* __restrict__ o, int nrows) {
  int w = (blockIdx.x * 256 + threadIdx.x) >> 6;
  int lane = threadIdx.x & 63;
  if (w >= nrows) return;
  const float* row = a + (size_t)w * DN;
  double s = 0.0;
  for (int i = lane; i < DN; i += 64) { double v = (double)row[i]; s = fma(v, v, s); }
#pragma unroll
  for (int off = 32; off; off >>= 1) s += __shfl_down(s, off);
  if (lane == 0) o[w] = s;
}

#define QT 64
#define DK 16
#define XLD 82     // fp64 x pitch (656B: 16B-aligned rows, bank-shift 4/row)
#define CLDf 260   // fp32 c pitch (1040B: 16B-aligned rows, bank-shift 4/row)
__device__ __forceinline__ int grow(int q) { return q + ((q >> 3) << 1); }

// dist -> softmax -> W. Hybrid LDS (x fp64 grouped, c fp32), register-pipelined.
__global__ __launch_bounds__(256, 2) void k_assign(const float* __restrict__ x,
                                                   const float* __restrict__ centers,
                                                   const double* __restrict__ csqd,
                                                   float* __restrict__ W) {
  __shared__ double xsD[DK][XLD];     // 10.5 KB
  __shared__ float  csF[DK][CLDf];    // 16.6 KB
  __shared__ double red[QT][33];      // 16.9 KB
  const int b = blockIdx.y, q0 = blockIdx.x * QT, t = threadIdx.x;
  const int rg = t & 7, cg = t >> 3;
  double acc[8][8];
#pragma unroll
  for (int i = 0; i < 8; i++)
#pragma unroll
    for (int j = 0; j < 8; j++) acc[i][j] = 0.0;

  const float* xb = x + ((size_t)b * QN + q0) * DN;
  const float* cb = centers + (size_t)b * LN * DN;
  const int xrow = t >> 2, xc4 = t & 3;
  const int xg = grow(xrow);

  float4 gx, gc[4];
  gx = *(const float4*)(xb + (size_t)xrow * DN + xc4 * 4);
#pragma unroll
  for (int i = 0; i < 4; i++) {
    int f = t + 256 * i; int row = f >> 2, c4 = f & 3;
    gc[i] = *(const float4*)(cb + (size_t)row * DN + c4 * 4);
  }

  for (int d0 = 0; d0 < DN; d0 += DK) {
    xsD[xc4 * 4 + 0][xg] = (double)gx.x; xsD[xc4 * 4 + 1][xg] = (double)gx.y;
    xsD[xc4 * 4 + 2][xg] = (double)gx.z; xsD[xc4 * 4 + 3][xg] = (double)gx.w;
#pragma unroll
    for (int i = 0; i < 4; i++) {
      int f = t + 256 * i; int row = f >> 2, c4 = f & 3;
      csF[c4 * 4 + 0][row] = gc[i].x; csF[c4 * 4 + 1][row] = gc[i].y;
      csF[c4 * 4 + 2][row] = gc[i].z; csF[c4 * 4 + 3][row] = gc[i].w;
    }
    __syncthreads();
    if (d0 + DK < DN) {   // global prefetch for next step
      gx = *(const float4*)(xb + (size_t)xrow * DN + (d0 + DK) + xc4 * 4);
#pragma unroll
      for (int i = 0; i < 4; i++) {
        int f = t + 256 * i; int row = f >> 2, c4 = f & 3;
        gc[i] = *(const float4*)(cb + (size_t)row * DN + (d0 + DK) + c4 * 4);
      }
    }
    // register-double-buffered inner loop
    double xva[8]; float4 ca0, ca1;
#pragma unroll
    for (int j = 0; j < 8; j++) xva[j] = xsD[0][rg * 10 + j];
    ca0 = *(const float4*)&csF[0][cg * 8];
    ca1 = *(const float4*)&csF[0][cg * 8 + 4];
#pragma unroll
    for (int k = 0; k < DK; k++) {
      double xvb[8]; float4 cb0, cb1;
      if (k + 1 < DK) {
#pragma unroll
        for (int j = 0; j < 8; j++) xvb[j] = xsD[k + 1][rg * 10 + j];
        cb0 = *(const float4*)&csF[k + 1][cg * 8];
        cb1 = *(const float4*)&csF[k + 1][cg * 8 + 4];
      }
      double cv[8] = {(double)ca0.x, (double)ca0.y, (double)ca0.z, (double)ca0.w,
                      (double)ca1.x, (double)ca1.y, (double)ca1.z, (double)ca1.w};
#pragma unroll
      for (int i = 0; i < 8; i++)
#pragma unroll
        for (int j = 0; j < 8; j++)
          acc[i][j] = fma(xva[i], cv[j], acc[i][j]);
      if (k + 1 < DK) {
#pragma unroll
        for (int j = 0; j < 8; j++) xva[j] = xvb[j];
        ca0 = cb0; ca1 = cb1;
      }
    }
    __syncthreads();
  }

  double csqv[8];
#pragma unroll
  for (int j = 0; j < 8; j++) csqv[j] = csqd[b * LN + cg * 8 + j];

  double lmax[8];
#pragma unroll
  for (int i = 0; i < 8; i++) {
    double m = -1e300;
#pragma unroll
    for (int j = 0; j < 8; j++) {
      double lg = -5.0 * (csqv[j] - 2.0 * acc[i][j]);
      acc[i][j] = lg;
      m = fmax(m, lg);
    }
    lmax[i] = m;
  }
#pragma unroll
  for (int i = 0; i < 8; i++) red[rg * 8 + i][cg] = lmax[i];
  __syncthreads();
  double rmax[8];
#pragma unroll
  for (int i = 0; i < 8; i++) {
    double m = -1e300;
    for (int c = 0; c < 32; c++) m = fmax(m, red[rg * 8 + i][c]);
    rmax[i] = m;
  }
  __syncthreads();
#pragma unroll
  for (int i = 0; i < 8; i++) {
    double s = 0.0;
#pragma unroll
    for (int j = 0; j < 8; j++) {
      double e = exp(acc[i][j] - rmax[i]);
      acc[i][j] = e;
      s += e;
    }
    red[rg * 8 + i][cg] = s;
  }
  __syncthreads();
#pragma unroll
  for (int i = 0; i < 8; i++) {
    double s = 0.0;
    for (int c = 0; c < 32; c++) s += red[rg * 8 + i][c];
    float* wrow = W + ((size_t)b * QN + q0 + rg * 8 + i) * LN + cg * 8;
    float4 v0 = make_float4((float)(acc[i][0] / s), (float)(acc[i][1] / s),
                            (float)(acc[i][2] / s), (float)(acc[i][3] / s));
    float4 v1 = make_float4((float)(acc[i][4] / s), (float)(acc[i][5] / s),
                            (float)(acc[i][6] / s), (float)(acc[i][7] / s));
    *(float4*)wrow = v0;
    *(float4*)(wrow + 4) = v1;
  }
}

// ---------------- split-K centroid update ----------------
#define NCH 8
#define CHQ (QN / NCH)   // 512
#define UKQ 16

// P[s][b][l][d] = sum_{q in chunk s} W[q][l]*X[q][d];  dsum[s][b][l] = sum w
__global__ __launch_bounds__(256, 2) void k_update_split(
    const float* __restrict__ W, const float* __restrict__ x,
    float* __restrict__ P, float* __restrict__ dsum) {
  __shared__ float wT[UKQ][132];
  __shared__ float xT[UKQ][132];
  const int b = blockIdx.z;
  const int s = blockIdx.y;
  const int lt = (blockIdx.x >> 2) * 128;
  const int dt = (blockIdx.x & 3) * 128;
  const int t = threadIdx.x;
  const int tr = t >> 4, tc = t & 15;
  float acc[8][8];
#pragma unroll
  for (int i = 0; i < 8; i++)
#pragma unroll
    for (int j = 0; j < 8; j++) acc[i][j] = 0.f;
  float dsm[8] = {0, 0, 0, 0, 0, 0, 0, 0};

  const float* Wb = W + ((size_t)b * QN + (size_t)s * CHQ) * LN + lt;
  const float* xb = x + ((size_t)b * QN + (size_t)s * CHQ) * DN + dt;

  float4 gw[2], gx2[2];
#pragma unroll
  for (int i = 0; i < 2; i++) {
    int f = t + 256 * i; int row = f >> 5, c = f & 31;
    gw[i]  = *(const float4*)(Wb + (size_t)row * LN + c * 4);
    gx2[i] = *(const float4*)(xb + (size_t)row * DN + c * 4);
  }

  for (int k0 = 0; k0 < CHQ; k0 += UKQ) {
#pragma unroll
    for (int i = 0; i < 2; i++) {
      int f = t + 256 * i; int row = f >> 5, c = f & 31;
      *(float4*)&wT[row][c * 4] = gw[i];
      *(float4*)&xT[row][c * 4] = gx2[i];
    }
    __syncthreads();
    if (k0 + UKQ < CHQ) {
#pragma unroll
      for (int i = 0; i < 2; i++) {
        int f = t + 256 * i; int row = f >> 5, c = f & 31;
        gw[i]  = *(const float4*)(Wb + (size_t)(k0 + UKQ + row) * LN + c * 4);
        gx2[i] = *(const float4*)(xb + (size_t)(k0 + UKQ + row) * DN + c * 4);
      }
    }
    // split-fragment reads: {base, base+64} 16B groups -> conflict-free
    float4 wa0, wa1, xa0, xa1;
    wa0 = *(const float4*)&wT[0][tr * 4];  wa1 = *(const float4*)&wT[0][64 + tr * 4];
    xa0 = *(const float4*)&xT[0][tc * 4];  xa1 = *(const float4*)&xT[0][64 + tc * 4];
#pragma unroll
    for (int k = 0; k < UKQ; k++) {
      float4 wb0, wb1, xb0, xb1;
      if (k + 1 < UKQ) {
        wb0 = *(const float4*)&wT[k + 1][tr * 4];  wb1 = *(const float4*)&wT[k + 1][64 + tr * 4];
        xb0 = *(const float4*)&xT[k + 1][tc * 4];  xb1 = *(const float4*)&xT[k + 1][64 + tc * 4];
      }
      float wf[8] = {wa0.x, wa0.y, wa0.z, wa0.w, wa1.x, wa1.y, wa1.z, wa1.w};
      float xf[8] = {xa0.x, xa0.y, xa0.z, xa0.w, xa1.x, xa1.y, xa1.z, xa1.w};
#pragma unroll
      for (int i = 0; i < 8; i++) {
        dsm[i] += wf[i];
#pragma unroll
        for (int j = 0; j < 8; j++) acc[i][j] = fmaf(wf[i], xf[j], acc[i][j]);
      }
      if (k + 1 < UKQ) { wa0 = wb0; wa1 = wb1; xa0 = xb0; xa1 = xb1; }
    }
    __syncthreads();
  }

#pragma unroll
  for (int i = 0; i < 8; i++) {
    int l = lt + ((i < 4) ? (tr * 4 + i) : (64 + tr * 4 + i - 4));
    float* prow = P + (((size_t)s * RB + b) * LN + l) * DN + dt;
    *(float4*)(prow + tc * 4)      = make_float4(acc[i][0], acc[i][1], acc[i][2], acc[i][3]);
    *(float4*)(prow + 64 + tc * 4) = make_float4(acc[i][4], acc[i][5], acc[i][6], acc[i][7]);
    if (tc == 0) dsum[((size_t)s * RB + b) * LN + l] = dsm[i];
  }
}

// Cnew = (sum_s P) / (sum_s dsum + eps); fused fp64 row sumsq -> csqd
__global__ __launch_bounds__(128) void k_reduce(const float* __restrict__ P,
                                                const float* __restrict__ dsum,
                                                float* __restrict__ cnew,
                                                double* __restrict__ csqd) {
  const int row = blockIdx.x;          // b*LN + l
  const int b = row >> 8, l = row & 255;
  const int t = threadIdx.x;
  float dn = 0.f;
#pragma unroll
  for (int s = 0; s < NCH; s++) dn += dsum[((size_t)s * RB + b) * LN + l];
  float den = dn + 1e-9f;
  float4 v = make_float4(0.f, 0.f, 0.f, 0.f);
#pragma unroll
  for (int s = 0; s < NCH; s++) {
    float4 p = *(const float4*)(P + (((size_t)s * RB + b) * LN + l) * DN + t * 4);
    v.x += p.x; v.y += p.y; v.z += p.z; v.w += p.w;
  }
  float4 o = make_float4(v.x / den, v.y / den, v.z / den, v.w / den);
  *(float4*)(cnew + ((size_t)b * LN + l) * DN + t * 4) = o;
  double sq = (double)o.x * o.x + (double)o.y * o.y +
              (double)o.z * o.z + (double)o.w * o.w;
#pragma unroll
  for (int off = 32; off; off >>= 1) sq += __shfl_down(sq, off);
  __shared__ double sred[2];
  if ((t & 63) == 0) sred[t >> 6] = sq;
  __syncthreads();
  if (t == 0) csqd[row] = sred[0] + sred[1];
}

// monolithic fallback update (round-4 version, used when ws is small)
#define LT 64
#define DT 64
#define KQ 32
__global__ __launch_bounds__(256) void k_update_mono(const float* __restrict__ W,
                                                     const float* __restrict__ x,
                                                     float* __restrict__ cnew) {
  __shared__ float wT[KQ][LT + 4];
  __shared__ float xT[KQ][DT + 4];
  const int b = blockIdx.z;
  const int l0 = blockIdx.x * LT;
  const int d0 = blockIdx.y * DT;
  const int t = threadIdx.x;
  const int rg = t & 15;
  const int cg = t >> 4;
  float acc[4][4];
#pragma unroll
  for (int i = 0; i < 4; i++)
#pragma unroll
    for (int j = 0; j < 4; j++) acc[i][j] = 0.f;
  float dsm[4] = {0.f, 0.f, 0.f, 0.f};
  const float* Wb = W + (size_t)b * QN * LN;
  const float* xb = x + (size_t)b * QN * DN;
  for (int k0 = 0; k0 < QN; k0 += KQ) {
#pragma unroll
    for (int i = 0; i < 2; i++) {
      int f = t + 256 * i;
      int row = f >> 4, c4 = f & 15;
      *(float4*)&wT[row][c4 * 4] = *(const float4*)(Wb + (size_t)(k0 + row) * LN + l0 + c4 * 4);
    }
#pragma unroll
    for (int i = 0; i < 2; i++) {
      int f = t + 256 * i;
      int row = f >> 4, c4 = f & 15;
      *(float4*)&xT[row][c4 * 4] = *(const float4*)(xb + (size_t)(k0 + row) * DN + d0 + c4 * 4);
    }
    __syncthreads();
#pragma unroll
    for (int k = 0; k < KQ; k++) {
      float wf[4], xf[4];
      *(float4*)wf = *(const float4*)&wT[k][rg * 4];
      *(float4*)xf = *(const float4*)&xT[k][cg * 4];
#pragma unroll
      for (int i = 0; i < 4; i++) {
        dsm[i] += wf[i];
#pragma unroll
        for (int j = 0; j < 4; j++) acc[i][j] = fmaf(wf[i], xf[j], acc[i][j]);
      }
    }
    __syncthreads();
  }
#pragma unroll
  for (int i = 0; i < 4; i++) {
    float den = dsm[i] + 1e-9f;
    *(float4*)(cnew + ((size_t)b * LN + l0 + rg * 4 + i) * DN + d0 + cg * 4) =
        make_float4(acc[i][0] / den, acc[i][1] / den, acc[i][2] / den, acc[i][3] / den);
  }
}

// fp64 dist -> argmin -> gather. Same pipelined GEMM as k_assign.
__global__ __launch_bounds__(256, 2) void k_final(const float* __restrict__ x,
                                                  const float* __restrict__ centers,
                                                  const double* __restrict__ csqd,
                                                  float* __restrict__ out) {
  __shared__ double xsD[DK][XLD];
  __shared__ float  csF[DK][CLDf];
  __shared__ double redv[QT][33];
  __shared__ unsigned short redi[QT][33];
  __shared__ unsigned short labels[QT];
  const int b = blockIdx.y, q0 = blockIdx.x * QT, t = threadIdx.x;
  const int rg = t & 7, cg = t >> 3;
  double acc[8][8];
#pragma unroll
  for (int i = 0; i < 8; i++)
#pragma unroll
    for (int j = 0; j < 8; j++) acc[i][j] = 0.0;

  const float* xb = x + ((size_t)b * QN + q0) * DN;
  const float* cb = centers + (size_t)b * LN * DN;
  const int xrow = t >> 2, xc4 = t & 3;
  const int xg = grow(xrow);

  float4 gx, gc[4];
  gx = *(const float4*)(xb + (size_t)xrow * DN + xc4 * 4);
#pragma unroll
  for (int i = 0; i < 4; i++) {
    int f = t + 256 * i; int row = f >> 2, c4 = f & 3;
    gc[i] = *(const float4*)(cb + (size_t)row * DN + c4 * 4);
  }

  for (int d0 = 0; d0 < DN; d0 += DK) {
    xsD[xc4 * 4 + 0][xg] = (double)gx.x; xsD[xc4 * 4 + 1][xg] = (double)gx.y;
    xsD[xc4 * 4 + 2][xg] = (double)gx.z; xsD[xc4 * 4 + 3][xg] = (double)gx.w;
#pragma unroll
    for (int i = 0; i < 4; i++) {
      int f = t + 256 * i; int row = f >> 2, c4 = f & 3;
      csF[c4 * 4 + 0][row] = gc[i].x; csF[c4 * 4 + 1][row] = gc[i].y;
      csF[c4 * 4 + 2][row] = gc[i].z; csF[c4 * 4 + 3][row] = gc[i].w;
    }
    __syncthreads();
    if (d0 + DK < DN) {
      gx = *(const float4*)(xb + (size_t)xrow * DN + (d0 + DK) + xc4 * 4);
#pragma unroll
      for (int i = 0; i < 4; i++) {
        int f = t + 256 * i; int row = f >> 2, c4 = f & 3;
        gc[i] = *(const float4*)(cb + (size_t)row * DN + (d0 + DK) + c4 * 4);
      }
    }
    double xva[8]; float4 ca0, ca1;
#pragma unroll
    for (int j = 0; j < 8; j++) xva[j] = xsD[0][rg * 10 + j];
    ca0 = *(const float4*)&csF[0][cg * 8];
    ca1 = *(const float4*)&csF[0][cg * 8 + 4];
#pragma unroll
    for (int k = 0; k < DK; k++) {
      double xvb[8]; float4 cb0, cb1;
      if (k + 1 < DK) {
#pragma unroll
        for (int j = 0; j < 8; j++) xvb[j] = xsD[k + 1][rg * 10 + j];
        cb0 = *(const float4*)&csF[k + 1][cg * 8];
        cb1 = *(const float4*)&csF[k + 1][cg * 8 + 4];
      }
      double cv[8] = {(double)ca0.x, (double)ca0.y, (double)ca0.z, (double)ca0.w,
                      (double)ca1.x, (double)ca1.y, (double)ca1.z, (double)ca1.w};
#pragma unroll
      for (int i = 0; i < 8; i++)
#pragma unroll
        for (int j = 0; j < 8; j++)
          acc[i][j] = fma(xva[i], cv[j], acc[i][j]);
      if (k + 1 < DK) {
#pragma unroll
        for (int j = 0; j < 8; j++) xva[j] = xvb[j];
        ca0 = cb0; ca1 = cb1;
      }
    }
    __syncthreads();
  }

  double csqv[8];
#pragma unroll
  for (int j = 0; j < 8; j++) csqv[j] = csqd[b * LN + cg * 8 + j];

  double bv[8]; int bi[8];
#pragma unroll
  for (int i = 0; i < 8; i++) {
    bv[i] = 1e300; bi[i] = 0;
#pragma unroll
    for (int j = 0; j < 8; j++) {
      double dd = csqv[j] - 2.0 * acc[i][j];
      if (dd < bv[i]) { bv[i] = dd; bi[i] = cg * 8 + j; }
    }
  }
#pragma unroll
  for (int i = 0; i < 8; i++) {
    redv[rg * 8 + i][cg] = bv[i];
    redi[rg * 8 + i][cg] = (unsigned short)bi[i];
  }
  __syncthreads();
  if (t < QT) {
    double best = 1e300; int bidx = 0;
    for (int c = 0; c < 32; c++) {
      double v = redv[t][c];
      int id = redi[t][c];
      if (v < best || (v == best && id < bidx)) { best = v; bidx = id; }
    }
    labels[t] = (unsigned short)bidx;
  }
  __syncthreads();
  const float4* cb4 = (const float4*)(centers + (size_t)b * LN * DN);
  float4* ob = (float4*)(out + ((size_t)b * QN + q0) * DN);
  for (int e = t; e < QT * (DN / 4); e += 256) {
    int row = e >> 7, c = e & 127;
    ob[(size_t)row * 128 + c] = cb4[(size_t)labels[row] * 128 + c];
  }
}

extern "C" void kernel_launch(void* const* d_in, const int* in_sizes, int n_in,
                              void* d_out, int out_size, void* d_ws, size_t ws_size,
                              hipStream_t stream) {
  const float* x = (const float*)d_in[0];
  float* out = (float*)d_out;

  const size_t szC    = (size_t)RB * LN * DN * sizeof(float);     // 4 MB
  const size_t szCsqD = (size_t)RB * LN * sizeof(double);         // 16 KB
  const size_t szDsum = (size_t)NCH * RB * LN * sizeof(float);    // 64 KB
  const size_t szW    = (size_t)RB * QN * LN * sizeof(float);     // 33.5 MB

  char* p = (char*)d_ws;
  float*  cA   = (float*)p;  p += szC;
  float*  cB   = (float*)p;  p += szC;
  double* csqd = (double*)p; p += szCsqD;
  float*  dsum = (float*)p;  p += szDsum;
  const bool bigws = ws_size >= 2 * szC + szCsqD + szDsum + szW;
  float* W = bigws ? (float*)p : (float*)d_out;
  float* P = (float*)d_out;   // split-K partials live in d_out (k_final rewrites)

  k_init<<<RB, 1024, 0, stream>>>(x, cA);
  k_rowsq_d<<<(RB * LN) / 4, 256, 0, stream>>>(cA, csqd, RB * LN);

  float* cur = cA;
  float* nxt = cB;
  for (int it = 0; it < NITERS; ++it) {
    k_assign<<<dim3(QN / QT, RB), 256, 0, stream>>>(x, cur, csqd, W);
    if (bigws) {
      k_update_split<<<dim3(8, NCH, RB), 256, 0, stream>>>(W, x, P, dsum);
      k_reduce<<<RB * LN, 128, 0, stream>>>(P, dsum, nxt, csqd);
    } else {
      k_update_mono<<<dim3(LN / LT, DN / DT, RB), 256, 0, stream>>>(W, x, nxt);
      k_rowsq_d<<<(RB * LN) / 4, 256, 0, stream>>>(nxt, csqd, RB * LN);
    }
    float* tmp = cur; cur = nxt; nxt = tmp;
  }
  k_final<<<dim3(QN / QT, RB), 256, 0, stream>>>(x, cur, csqd, out);
}